// Round 13
// baseline (433.739 us; speedup 1.0000x reference)
//
#include <hip/hip_runtime.h>
#include <stdint.h>

// ---------------------------------------------------------------------------
// Conv-SNN, 100 steps, B=64, BETA=0.
// Round 13: fixup straggler fix — compact flagged bits into dense worklists.
//  - r12 fix2: 86 us at Occupancy 3.3% / VALUBusy 4% (sparse heavy threads).
//  - compact1/2: scan F-words, atomicAdd-reserve popcount slots, entry
//    e = wordIdx*32 + bit (bit==oc in both A1 and A2 word layouts).
//  - fix1b/2b: grid-stride dense threads, one per flagged bit, exact f64
//    recompute (same summation order), single-bit atomicOr/And patch.
// All other kernels byte-identical to round 12 (absmax 0.0 lineage).
// ---------------------------------------------------------------------------

#define NSTEPS 100
#define NB 64
#define CAPF1 2000000u
#define CAPF2 1000000u

typedef short bf16x8 __attribute__((ext_vector_type(8)));
typedef float f32x4 __attribute__((ext_vector_type(4)));

__device__ __forceinline__ uint32_t rotl32(uint32_t v, uint32_t r) {
  return (v << r) | (v >> (32u - r));
}

__device__ __forceinline__ void threefry2x32(uint32_t k0, uint32_t k1,
                                             uint32_t& x0, uint32_t& x1) {
  uint32_t k2 = k0 ^ k1 ^ 0x1BD11BDAu;
  x0 += k0; x1 += k1;
#define TF_R(r) { x0 += x1; x1 = rotl32(x1, r); x1 ^= x0; }
  TF_R(13u) TF_R(15u) TF_R(26u) TF_R(6u)
  x0 += k1; x1 += k2 + 1u;
  TF_R(17u) TF_R(29u) TF_R(16u) TF_R(24u)
  x0 += k2; x1 += k0 + 2u;
  TF_R(13u) TF_R(15u) TF_R(26u) TF_R(6u)
  x0 += k0; x1 += k1 + 3u;
  TF_R(17u) TF_R(29u) TF_R(16u) TF_R(24u)
  x0 += k1; x1 += k2 + 4u;
  TF_R(13u) TF_R(15u) TF_R(26u) TF_R(6u)
  x0 += k2; x1 += k0 + 5u;
#undef TF_R
}

__device__ __forceinline__ double fold_pool_w(const float* W, int base, int pos) {
  int iy = pos / 6, ix = pos % 6;
  double w = 0.0;
  for (int dy = 0; dy < 2; ++dy) {
    int ky = iy - dy; if (ky < 0 || ky > 4) continue;
    for (int dx = 0; dx < 2; ++dx) {
      int kx = ix - dx; if (kx < 0 || kx > 4) continue;
      w += (double)W[base + ky * 5 + kx];
    }
  }
  return w;
}

__device__ __forceinline__ uint16_t f2bf(float x) {  // RNE bf16
  uint32_t u = __float_as_uint(x);
  uint32_t r = (u + 0x7fffu + ((u >> 16) & 1u)) >> 16;
  return (uint16_t)r;
}

// f64 masters: W1R [og4][pos36][c3][oj8], W2R [og4][c32][pos36][oj16]
__global__ __launch_bounds__(256) void weff_all(const float* __restrict__ W_in,
                                                const float* __restrict__ W_h1,
                                                double* __restrict__ W1R,
                                                double* __restrict__ W2R) {
  int e = blockIdx.x * 256 + threadIdx.x;
  if (e < 3456) {
    int oj = e & 7, c = (e >> 3) % 3, pos = ((e >> 3) / 3) % 36, og = (e >> 3) / 108;
    int oc = og * 8 + oj;
    W1R[e] = fold_pool_w(W_in, (oc * 3 + c) * 25, pos);
  } else if (e < 3456 + 73728) {
    int e2 = e - 3456;
    int oj = e2 & 15, pos = (e2 >> 4) % 36, c = ((e2 >> 4) / 36) % 32, og = e2 / 18432;
    int oc = og * 16 + oj;
    W2R[e2] = fold_pool_w(W_h1, (oc * 32 + c) * 25, pos);
  }
}

// conv1 MFMA B-frags: WB1[hl2][ks4][nt2][lane64][j8] bf16; k = c*36+pos.
__global__ __launch_bounds__(256) void wprep1b(const float* __restrict__ W_in,
                                               uint16_t* __restrict__ WB1) {
  int e = blockIdx.x * 256 + threadIdx.x;
  if (e >= 16384) return;
  int j = e & 7, lane = (e >> 3) & 63, nt = (e >> 9) & 1, ks = (e >> 10) & 3, hl = e >> 12;
  int k = ks * 32 + (lane >> 4) * 8 + j;
  int oc = nt * 16 + (lane & 15);
  uint16_t val = 0;
  if (k < 108) {
    int c = k / 36, pos = k % 36;
    double w = fold_pool_w(W_in, (oc * 3 + c) * 25, pos);
    uint16_t hi = f2bf((float)w);
    if (hl == 0) val = hi;
    else {
      float hif = __uint_as_float(((uint32_t)hi) << 16);
      val = f2bf((float)(w - (double)hif));
    }
  }
  WB1[e] = val;
}

// conv2 MFMA B-frags: WB2[hl2][pos36][nt4][lane64][j8] bf16
__global__ __launch_bounds__(256) void wprep2(const float* __restrict__ W_h1,
                                              uint16_t* __restrict__ WB) {
  int e = blockIdx.x * 256 + threadIdx.x;
  if (e >= 36 * 4 * 64 * 8) return;
  int j = e & 7, lane = (e >> 3) & 63, nt = (e >> 9) & 3, pos = e >> 11;
  int oc = nt * 16 + (lane & 15);
  int c  = (lane >> 4) * 8 + j;
  double w = fold_pool_w(W_h1, (oc * 32 + c) * 25, pos);
  uint16_t hi = f2bf((float)w);
  float hif = __uint_as_float(((uint32_t)hi) << 16);
  uint16_t lo = f2bf((float)(w - (double)hif));
  WB[e] = hi;
  WB[73728 + e] = lo;
}

// EPS[0..31]: conv1 per-oc flag radius; EPS[32..95]: conv2 per-oc.
__global__ __launch_bounds__(128) void eps_kernel(const double* __restrict__ W1R,
                                                  const double* __restrict__ W2R,
                                                  float* __restrict__ EPS) {
  int oc = blockIdx.x * 128 + threadIdx.x;
  const double u24 = 5.9604644775390625e-08;
  if (oc < 32) {
    int og = oc >> 3, oj = oc & 7;
    double S = 0.0;
    for (int pos = 0; pos < 36; ++pos)
      for (int c = 0; c < 3; ++c) S += fabs(W1R[og * 864 + pos * 24 + c * 8 + oj]);
    EPS[oc] = (float)(S * (108.0 * u24 * 6.0) * 0.25);
  } else if (oc < 96) {
    int o = oc - 32, og = o >> 4, oj = o & 15;
    double S = 0.0;
    for (int c = 0; c < 32; ++c)
      for (int pos = 0; pos < 36; ++pos) S += fabs(W2R[og * 18432 + c * 576 + pos * 16 + oj]);
    EPS[oc] = (float)(S * (1152.0 * u24 * 6.0) * 0.25);
  }
}

// --- spike gen via ballot: rowm[tb][c][32 rows] u32 -----------------------
__global__ __launch_bounds__(256) void gen_spikes(const float* __restrict__ x,
                                                  uint32_t* __restrict__ rowm) {
  int id = blockIdx.x * 4 + (threadIdx.x >> 6);
  int lane = threadIdx.x & 63;
  int rp = id & 15, c = (id >> 4) % 3, tb = id / 48;
  int pix = rp * 64 + lane;
  int b = tb & 63;
  uint32_t i = (uint32_t)((tb * 3 + c) * 1024 + pix);
  uint32_t x0 = 0u, x1 = i;
  threefry2x32(0u, 1u, x0, x1);
  uint32_t bits = x0 ^ x1;
  float u = __uint_as_float((bits >> 9) | 0x3f800000u) - 1.0f;
  float xv = x[(b * 3 + c) * 1024 + pix];
  unsigned long long mask = __ballot(u < 2.0f * xv);
  if (lane == 0) ((unsigned long long*)rowm)[id] = mask;
}

// --- win_prep: per (tb, pixel) pack 108-bit K-window (k=c*36+pos) ---------
__global__ __launch_bounds__(256) void win_prep(const uint32_t* __restrict__ rowm,
                                                uint4* __restrict__ win1) {
  const int tb = blockIdx.x;
  const int tid = threadIdx.x;
  __shared__ uint32_t sR[96];
  if (tid < 96) sR[tid] = rowm[tb * 96 + tid];
  __syncthreads();
  if (tid < 196) {
    int oh = tid / 14, ow = tid % 14;
    uint64_t seg[3];
    #pragma unroll
    for (int c = 0; c < 3; ++c) {
      uint64_t s = 0;
      #pragma unroll
      for (int iy = 0; iy < 6; ++iy)
        s |= (uint64_t)((sR[c * 32 + 2 * oh + iy] >> (2 * ow)) & 0x3fu) << (6 * iy);
      seg[c] = s;
    }
    uint64_t lo = seg[0] | (seg[1] << 36);
    uint64_t hi = (seg[1] >> 28) | (seg[2] << 8);
    uint4 w;
    w.x = (uint32_t)lo; w.y = (uint32_t)(lo >> 32);
    w.z = (uint32_t)hi; w.w = (uint32_t)(hi >> 32);
    win1[tb * 196 + tid] = w;
  }
}

// --- conv1 via MFMA (unchanged) -------------------------------------------
__global__ __launch_bounds__(256) void conv1_mfma(const uint4* __restrict__ win1,
                                                  const uint16_t* __restrict__ WB1,
                                                  const float* __restrict__ EPS,
                                                  uint32_t* __restrict__ A1w,
                                                  uint32_t* __restrict__ B1w,
                                                  uint32_t* __restrict__ F1w) {
  const int tid = threadIdx.x;
  const int wid = tid >> 6, lane = tid & 63;
  const int tb = blockIdx.x * 4 + wid;
  const int q = lane >> 4, ln = lane & 15;

  const float eps0 = EPS[ln];
  const float eps1 = EPS[16 + ln];

  bf16x8 bf[2][4][2];
  #pragma unroll
  for (int hl = 0; hl < 2; ++hl)
    #pragma unroll
    for (int ks = 0; ks < 4; ++ks)
      #pragma unroll
      for (int nt = 0; nt < 2; ++nt)
        bf[hl][ks][nt] =
            *(const bf16x8*)(WB1 + ((((hl * 4 + ks) * 2 + nt) * 64 + lane) * 8));

  const int wl = lane;
  const int qq = wl >> 2, rr = wl & 3;

  for (int mt = 0; mt < 13; ++mt) {
    int p = mt * 16 + ln;
    int pc = p < 196 ? p : 195;
    uint4 win = win1[tb * 196 + pc];
    uint32_t wz[4] = {win.x, win.y, win.z, win.w};

    f32x4 acc0 = (f32x4)(0.0f), acc1 = (f32x4)(0.0f);
    #pragma unroll
    for (int ks = 0; ks < 4; ++ks) {
      uint32_t byte = (wz[ks] >> (q * 8)) & 0xffu;
      union { uint32_t u[4]; bf16x8 v; } a;
      #pragma unroll
      for (int i = 0; i < 4; ++i)
        a.u[i] = (((byte >> (2 * i)) & 1u) ? 0x3F80u : 0u) |
                 (((byte >> (2 * i + 1)) & 1u) ? 0x3F800000u : 0u);
      acc0 = __builtin_amdgcn_mfma_f32_16x16x32_bf16(a.v, bf[0][ks][0], acc0, 0, 0, 0);
      acc0 = __builtin_amdgcn_mfma_f32_16x16x32_bf16(a.v, bf[1][ks][0], acc0, 0, 0, 0);
      acc1 = __builtin_amdgcn_mfma_f32_16x16x32_bf16(a.v, bf[0][ks][1], acc1, 0, 0, 0);
      acc1 = __builtin_amdgcn_mfma_f32_16x16x32_bf16(a.v, bf[1][ks][1], acc1, 0, 0, 0);
    }

    unsigned long long bA0[4], bA1[4], bB0[4], bB1[4], bF0[4], bF1[4];
    #pragma unroll
    for (int r = 0; r < 4; ++r) {
      float c0 = acc0[r] * 0.25f;
      float c1 = acc1[r] * 0.25f;
      bA0[r] = __ballot(c0 > 1.0f);
      bB0[r] = __ballot(c0 > 2.0f);
      bF0[r] = __ballot(fabsf(c0 - 1.0f) <= eps0 || fabsf(c0 - 2.0f) <= eps0);
      bA1[r] = __ballot(c1 > 1.0f);
      bB1[r] = __ballot(c1 > 2.0f);
      bF1[r] = __ballot(fabsf(c1 - 1.0f) <= eps1 || fabsf(c1 - 2.0f) <= eps1);
    }

    int pw = mt * 16 + wl;
    if (wl < 16 && pw < 196) {
#define SEL(B) (rr == 0 ? B[0] : rr == 1 ? B[1] : rr == 2 ? B[2] : B[3])
      uint32_t wA = (uint32_t)((SEL(bA0) >> (qq * 16)) & 0xffffull) |
                    ((uint32_t)((SEL(bA1) >> (qq * 16)) & 0xffffull) << 16);
      uint32_t wB = (uint32_t)((SEL(bB0) >> (qq * 16)) & 0xffffull) |
                    ((uint32_t)((SEL(bB1) >> (qq * 16)) & 0xffffull) << 16);
      uint32_t wF = (uint32_t)((SEL(bF0) >> (qq * 16)) & 0xffffull) |
                    ((uint32_t)((SEL(bF1) >> (qq * 16)) & 0xffffull) << 16);
#undef SEL
      uint32_t idx = (uint32_t)(tb * 196 + pw);
      A1w[idx] = wA;
      B1w[idx] = wB;
      F1w[idx] = wF;
    }
  }
}

// --- compaction: flagged bits -> dense worklist (e = wordIdx*32 + bit) ----
__global__ __launch_bounds__(256) void compact_flags(const uint32_t* __restrict__ Fw,
                                                     int nwords,
                                                     uint32_t* __restrict__ cnt,
                                                     uint32_t* __restrict__ list,
                                                     uint32_t cap) {
  int wi = blockIdx.x * 256 + threadIdx.x;
  if (wi >= nwords) return;
  uint32_t w = Fw[wi];
  if (!w) return;
  uint32_t n = (uint32_t)__popc(w);
  uint32_t slot = atomicAdd(cnt, n);
  while (w) {
    int bit = __ffs(w) - 1;
    w &= w - 1;
    if (slot < cap) list[slot] = (uint32_t)wi * 32u + (uint32_t)bit;
    ++slot;
  }
}

// --- fix1b: dense worklist, exact f64, single-bit atomic patch ------------
__global__ __launch_bounds__(64) void fix1b(const uint32_t* __restrict__ cnt,
                                            const uint32_t* __restrict__ list,
                                            const uint32_t* __restrict__ rowm,
                                            const double* __restrict__ W1R,
                                            uint32_t* __restrict__ A1w,
                                            uint32_t* __restrict__ B1w) {
  uint32_t total = cnt[0]; if (total > CAPF1) total = CAPF1;
  for (uint32_t i = blockIdx.x * 64 + threadIdx.x; i < total; i += gridDim.x * 64) {
    uint32_t e = list[i];
    uint32_t x = e >> 5;         // word index == output index (tb*196+p)
    int oc = (int)(e & 31u);
    int tb = (int)(x / 196), p = (int)(x % 196);
    int oh = p / 14, ow = p % 14;
    int og = oc >> 3, oj = oc & 7;
    const uint32_t* R = rowm + (size_t)tb * 96;
    double acc = 0.0;
    for (int iy = 0; iy < 6; ++iy)
      for (int ix = 0; ix < 6; ++ix)
        for (int c = 0; c < 3; ++c) {
          double bd = (double)((R[c * 32 + 2 * oh + iy] >> (2 * ow + ix)) & 1u);
          acc = fma(bd, W1R[og * 864 + (iy * 6 + ix) * 24 + c * 8 + oj], acc);
        }
    float cur = (float)(acc * 0.25);
    uint32_t m = 1u << oc;       // bit oc within word x
    if (cur > 1.0f) atomicOr(&A1w[x], m); else atomicAnd(&A1w[x], ~m);
    if (cur > 2.0f) atomicOr(&B1w[x], m); else atomicAnd(&B1w[x], ~m);
  }
}

// --- LIF1 scan (unchanged) -------------------------------------------------
__global__ __launch_bounds__(64) void scan1(const uint32_t* __restrict__ A1w,
                                            const uint32_t* __restrict__ B1w,
                                            uint32_t* __restrict__ mask1) {
  int chain = blockIdx.x * 64 + threadIdx.x;
  if (chain >= NB * 196) return;
  int b = chain / 196, p = chain % 196;
  const size_t stride = (size_t)NB * 196;
  size_t base = (size_t)b * 196 + p;
  uint32_t prev = 0;
  #pragma unroll
  for (int seg = 0; seg < 4; ++seg) {
    uint32_t Abuf[25], Bbuf[25];
    size_t sb = base + (size_t)(seg * 25) * stride;
    #pragma unroll
    for (int i = 0; i < 25; ++i) {
      Abuf[i] = A1w[sb + i * stride];
      Bbuf[i] = B1w[sb + i * stride];
    }
    #pragma unroll
    for (int i = 0; i < 25; ++i) {
      uint32_t s = (Abuf[i] & ~prev) | (Bbuf[i] & prev);
      mask1[sb + i * stride] = s;
      prev = s;
    }
  }
}

// --- conv2 via MFMA, ballot epilogue (unchanged from r12) -----------------
__global__ __launch_bounds__(256, 4) void conv2_mfma(const uint32_t* __restrict__ mask1,
                                                     const uint16_t* __restrict__ WB,
                                                     const float* __restrict__ EPS,
                                                     uint32_t* __restrict__ A2w,
                                                     uint32_t* __restrict__ B2w,
                                                     uint32_t* __restrict__ F2w) {
  __shared__ uint32_t sM[4 * 196];
  const int tid = threadIdx.x;
  const int wid = tid >> 6, lane = tid & 63;
  const int tb = blockIdx.x * 4 + wid;

  {
    const uint32_t* src = mask1 + (size_t)tb * 196;
    for (int i = lane; i < 196; i += 64) sM[wid * 196 + i] = src[i];
  }
  __syncthreads();

  const int q  = lane >> 4;
  const int ln = lane & 15;
  float epsv[4];
  #pragma unroll
  for (int nt = 0; nt < 4; ++nt) epsv[nt] = EPS[32 + nt * 16 + ln];

  const int p0 = ln;
  const int p1 = 16 + ln;
  const bool v1 = (p1 < 25);
  const int oh0 = p0 / 5, ow0 = p0 % 5;
  const int p1c = v1 ? p1 : 0;
  const int oh1 = p1c / 5, ow1 = p1c % 5;

  f32x4 acc[8];
  #pragma unroll
  for (int i = 0; i < 8; ++i) acc[i] = (f32x4)(0.0f);

  const uint32_t* sMw = &sM[wid * 196];

  for (int iy = 0; iy < 6; ++iy) {
    #pragma unroll
    for (int ix = 0; ix < 6; ++ix) {
      const int pos = iy * 6 + ix;
      uint32_t w0 = sMw[(2 * oh0 + iy) * 14 + 2 * ow0 + ix];
      uint32_t w1 = v1 ? sMw[(2 * oh1 + iy) * 14 + 2 * ow1 + ix] : 0u;
      uint32_t bits0 = (w0 >> (q * 8)) & 0xffu;
      uint32_t bits1 = (w1 >> (q * 8)) & 0xffu;
      union { uint32_t u[4]; bf16x8 v; } a0, a1;
      #pragma unroll
      for (int i = 0; i < 4; ++i) {
        a0.u[i] = (((bits0 >> (2 * i)) & 1u) ? 0x3F80u : 0u) |
                  (((bits0 >> (2 * i + 1)) & 1u) ? 0x3F800000u : 0u);
        a1.u[i] = (((bits1 >> (2 * i)) & 1u) ? 0x3F80u : 0u) |
                  (((bits1 >> (2 * i + 1)) & 1u) ? 0x3F800000u : 0u);
      }
      const uint16_t* bhi_base = WB + (size_t)pos * 2048 + lane * 8;
      const uint16_t* blo_base = bhi_base + 73728;
      #pragma unroll
      for (int nt = 0; nt < 4; ++nt) {
        bf16x8 bhi = *(const bf16x8*)(bhi_base + nt * 512);
        bf16x8 blo = *(const bf16x8*)(blo_base + nt * 512);
        acc[nt] = __builtin_amdgcn_mfma_f32_16x16x32_bf16(a0.v, bhi, acc[nt], 0, 0, 0);
        acc[nt] = __builtin_amdgcn_mfma_f32_16x16x32_bf16(a0.v, blo, acc[nt], 0, 0, 0);
        acc[4 + nt] = __builtin_amdgcn_mfma_f32_16x16x32_bf16(a1.v, bhi, acc[4 + nt], 0, 0, 0);
        acc[4 + nt] = __builtin_amdgcn_mfma_f32_16x16x32_bf16(a1.v, blo, acc[4 + nt], 0, 0, 0);
      }
    }
  }

  const int w = lane;
  const int pw = w >> 1, hfw = w & 1;
  #pragma unroll
  for (int mt2 = 0; mt2 < 2; ++mt2) {
    const int pt = pw - mt2 * 16;
    const bool wvalid = (w < 50) && (pt >= 0) && (pt < 16) && (pw < 25);
    const int qw = (pt & 15) >> 2, rw = pt & 3;
    uint32_t wA = 0, wB = 0, wF = 0;
    #pragma unroll
    for (int nt = 0; nt < 4; ++nt) {
      unsigned long long bA[4], bB[4], bF[4];
      #pragma unroll
      for (int reg = 0; reg < 4; ++reg) {
        float c = acc[mt2 * 4 + nt][reg] * 0.25f;
        float e = epsv[nt];
        bA[reg] = __ballot(c > 1.0f);
        bB[reg] = __ballot(c > 2.0f);
        bF[reg] = __ballot(fabsf(c - 1.0f) <= e || fabsf(c - 2.0f) <= e);
      }
      if (wvalid && (nt >> 1) == hfw) {
        const int sh = (nt & 1) * 16;
#define SEL(B) (rw == 0 ? B[0] : rw == 1 ? B[1] : rw == 2 ? B[2] : B[3])
        wA |= (uint32_t)((SEL(bA) >> (qw * 16)) & 0xffffull) << sh;
        wB |= (uint32_t)((SEL(bB) >> (qw * 16)) & 0xffffull) << sh;
        wF |= (uint32_t)((SEL(bF) >> (qw * 16)) & 0xffffull) << sh;
#undef SEL
      }
    }
    if (wvalid) {
      uint32_t idx = (uint32_t)(tb * 25 + pw) * 2 + hfw;
      A2w[idx] = wA;
      B2w[idx] = wB;
      F2w[idx] = wF;
    }
  }
}

// --- fix2b: dense worklist, exact f64, single-bit atomic patch ------------
__global__ __launch_bounds__(64) void fix2b(const uint32_t* __restrict__ cnt,
                                            const uint32_t* __restrict__ list,
                                            const uint32_t* __restrict__ mask1,
                                            const double* __restrict__ W2R,
                                            uint32_t* __restrict__ A2w,
                                            uint32_t* __restrict__ B2w) {
  uint32_t total = cnt[1]; if (total > CAPF2) total = CAPF2;
  for (uint32_t i = blockIdx.x * 64 + threadIdx.x; i < total; i += gridDim.x * 64) {
    uint32_t e = list[i];
    uint32_t wi = e >> 5;        // A2 word index = x*2 + (oc>>5)
    int bit = (int)(e & 31u);
    uint32_t x = wi >> 1;        // tb*25 + p
    int oc = (int)((wi & 1u) * 32u) + bit;
    int tb = (int)(x / 25), p = (int)(x % 25);
    int oh = p / 5, ow = p % 5;
    int og = oc >> 4, oj = oc & 15;
    const uint32_t* M = mask1 + (size_t)tb * 196;
    double acc = 0.0;
    for (int c = 0; c < 32; ++c)
      for (int iy = 0; iy < 6; ++iy)
        for (int ix = 0; ix < 6; ++ix) {
          uint32_t mm = M[(2 * oh + iy) * 14 + 2 * ow + ix];
          double bd = (double)((mm >> c) & 1u);
          acc = fma(bd, W2R[og * 18432 + c * 576 + (iy * 6 + ix) * 16 + oj], acc);
        }
    float cur = (float)(acc * 0.25);
    uint32_t m = 1u << bit;
    if (cur > 1.0f) atomicOr(&A2w[wi], m); else atomicAnd(&A2w[wi], ~m);
    if (cur > 2.0f) atomicOr(&B2w[wi], m); else atomicAnd(&B2w[wi], ~m);
  }
}

// --- LIF2 scan (unchanged) -------------------------------------------------
__global__ __launch_bounds__(64) void scan2(const uint64_t* __restrict__ A2q,
                                            const uint64_t* __restrict__ B2q,
                                            uint64_t* __restrict__ mask2) {
  int chain = blockIdx.x * 64 + threadIdx.x;
  if (chain >= NB * 25) return;
  int b = chain / 25, p = chain % 25;
  const size_t stride = (size_t)NB * 25;
  size_t base = (size_t)b * 25 + p;
  uint64_t prev = 0;
  #pragma unroll
  for (int seg = 0; seg < 4; ++seg) {
    uint64_t Abuf[25], Bbuf[25];
    size_t sb = base + (size_t)(seg * 25) * stride;
    #pragma unroll
    for (int i = 0; i < 25; ++i) {
      Abuf[i] = A2q[sb + i * stride];
      Bbuf[i] = B2q[sb + i * stride];
    }
    #pragma unroll
    for (int i = 0; i < 25; ++i) {
      uint64_t s = (Abuf[i] & ~prev) | (Bbuf[i] & prev);
      mask2[sb + i * stride] = s;
      prev = s;
    }
  }
}

// --- FC (unchanged) --------------------------------------------------------
__global__ __launch_bounds__(256) void fc_kernel(const uint64_t* __restrict__ mask2,
                                                 const float* __restrict__ W2,
                                                 float* __restrict__ cur3) {
  int gid = blockIdx.x * 256 + threadIdx.x;
  if (gid >= NSTEPS * NB * 80) return;
  int tb = gid / 80, r = gid % 80;
  int o = r >> 3, s = r & 7;
  const uint64_t* m = mask2 + (size_t)tb * 25;
  const float* w = W2 + o * 1600 + s * 200;

  uint64_t mw[25];
  #pragma unroll
  for (int p = 0; p < 25; ++p) mw[p] = m[p];

  const int oc0 = s * 8;
  double acc0 = 0.0, acc1 = 0.0;
  #pragma unroll
  for (int j = 0; j < 8; ++j) {
    const float* wj = w + j * 25;
    double a = 0.0;
    #pragma unroll
    for (int p = 0; p < 25; ++p) {
      double bd = (double)((mw[p] >> (oc0 + j)) & 1ull);
      a = fma(bd, (double)wj[p], a);
    }
    if (j & 1) acc1 += a; else acc0 += a;
  }
  double acc = acc0 + acc1;
  acc += __shfl_xor(acc, 4);
  acc += __shfl_xor(acc, 2);
  acc += __shfl_xor(acc, 1);
  if (s == 0) cur3[tb * 10 + o] = (float)acc;
}

// --- LIF3 (unchanged) ------------------------------------------------------
__global__ __launch_bounds__(64) void lif3_kernel(const float* __restrict__ cur3,
                                                  float* __restrict__ out) {
  int bo = blockIdx.x * 64 + threadIdx.x;
  if (bo >= NB * 10) return;
  float prev = 0.0f;
  #pragma unroll
  for (int seg = 0; seg < 4; ++seg) {
    float cbuf[25];
    #pragma unroll
    for (int i = 0; i < 25; ++i) cbuf[i] = cur3[(seg * 25 + i) * 640 + bo];
    #pragma unroll
    for (int i = 0; i < 25; ++i) {
      int t = seg * 25 + i;
      float mem = cbuf[i] - prev;
      bool s = mem > 1.0f;
      out[t * 640 + bo] = s ? 1.0f : 0.0f;
      out[NSTEPS * 640 + t * 640 + bo] = mem;
      prev = s ? 1.0f : 0.0f;
    }
  }
}

extern "C" void kernel_launch(void* const* d_in, const int* in_sizes, int n_in,
                              void* d_out, int out_size, void* d_ws, size_t ws_size,
                              hipStream_t stream) {
  const float* x    = (const float*)d_in[0];
  const float* W_in = (const float*)d_in[1];
  const float* W_h1 = (const float*)d_in[2];
  const float* W_h2 = (const float*)d_in[3];
  float* out = (float*)d_out;

  unsigned char* ws = (unsigned char*)d_ws;
  double*        W1R   = (double*)(ws + 0);            //     27,648
  double*        W2R   = (double*)(ws + 27648);        //    589,824
  uint16_t*      WB1   = (uint16_t*)(ws + 617472);     //     32,768
  uint16_t*      WB2   = (uint16_t*)(ws + 650240);     //    294,912
  float*         EPS   = (float*)(ws + 945152);        //        384
  uint32_t*      cnt   = (uint32_t*)(ws + 945536);     //          8 (pad 128)
  uint32_t*      rowm  = (uint32_t*)(ws + 945664);     //  2,457,600
  uint4*         win1  = (uint4*)(ws + 3403776);       // 20,070,400 (945664+2457600=3403264, pad to 3403776)
  unsigned char* A1    = ws + 23474176;                //  5,017,600
  unsigned char* B1    = ws + 28491776;                //  5,017,600
  unsigned char* F1    = ws + 33509376;                //  5,017,600
  uint32_t*      mask1 = (uint32_t*)(ws + 38526976);   //  5,017,600
  unsigned char* A2    = ws + 43544576;                //  1,280,000
  unsigned char* B2    = ws + 44824576;                //  1,280,000
  unsigned char* F2    = ws + 46104576;                //  1,280,000
  uint64_t*      mask2 = (uint64_t*)(ws + 47384576);   //  1,280,000
  float*         cur3  = (float*)(ws + 48664576);      //    256,000
  uint32_t*      list1 = (uint32_t*)(ws + 48920576);   //  8,000,000 (CAPF1)
  uint32_t*      list2 = (uint32_t*)(ws + 56920576);   //  4,000,000 (end ~61 MB)

  weff_all<<<302, 256, 0, stream>>>(W_in, W_h1, W1R, W2R);
  wprep1b<<<64, 256, 0, stream>>>(W_in, WB1);
  wprep2<<<288, 256, 0, stream>>>(W_h1, WB2);
  eps_kernel<<<1, 128, 0, stream>>>(W1R, W2R, EPS);
  hipMemsetAsync(cnt, 0, 8, stream);
  gen_spikes<<<76800, 256, 0, stream>>>(x, rowm);
  win_prep<<<6400, 256, 0, stream>>>(rowm, win1);
  conv1_mfma<<<1600, 256, 0, stream>>>(win1, WB1, EPS,
                                       (uint32_t*)A1, (uint32_t*)B1, (uint32_t*)F1);
  compact_flags<<<(1254400 + 255) / 256, 256, 0, stream>>>((const uint32_t*)F1, 1254400,
                                                           &cnt[0], list1, CAPF1);
  fix1b<<<1024, 64, 0, stream>>>(cnt, list1, rowm, W1R, (uint32_t*)A1, (uint32_t*)B1);
  scan1<<<(NB * 196 + 63) / 64, 64, 0, stream>>>((const uint32_t*)A1,
                                                 (const uint32_t*)B1, mask1);
  conv2_mfma<<<1600, 256, 0, stream>>>(mask1, WB2, EPS,
                                       (uint32_t*)A2, (uint32_t*)B2, (uint32_t*)F2);
  compact_flags<<<(320000 + 255) / 256, 256, 0, stream>>>((const uint32_t*)F2, 320000,
                                                          &cnt[1], list2, CAPF2);
  fix2b<<<1024, 64, 0, stream>>>(cnt, list2, mask1, W2R, (uint32_t*)A2, (uint32_t*)B2);
  scan2<<<(NB * 25 + 63) / 64, 64, 0, stream>>>((const uint64_t*)A2,
                                                (const uint64_t*)B2, mask2);
  fc_kernel<<<(NSTEPS * NB * 80 + 255) / 256, 256, 0, stream>>>(mask2, W_h2, cur3);
  lif3_kernel<<<10, 64, 0, stream>>>(cur3, out);
}

// Round 14
// 349.825 us; speedup vs baseline: 1.2399x; 1.2399x over previous
//
#include <hip/hip_runtime.h>
#include <stdint.h>

// ---------------------------------------------------------------------------
// Conv-SNN, 100 steps, B=64, BETA=0.
// Round 14: launch-count attack (17 -> 10 kernels; ~10us/launch overhead
// identified from r12->r13 regression) + conv2 2-tb-per-wave B reuse.
//  - prep_all: weff+wprep1b+wprep2+eps+cnt-zero in one kernel.
//  - conv1_mfma: builds K-windows from rowm in-kernel (win1 buffer deleted),
//    flag bits appended to worklist in-epilogue (F1 deleted).
//  - conv2_mfma: 2 tb per wave (B-frags amortized), wave-local LDS (no
//    barrier), in-epilogue flag append (F2 deleted).
// Exactness machinery unchanged: bf16 hi/lo MFMA + eps flags + f64 fixup.
// ---------------------------------------------------------------------------

#define NSTEPS 100
#define NB 64
#define CAPF1 524288u
#define CAPF2 262144u

typedef short bf16x8 __attribute__((ext_vector_type(8)));
typedef float f32x4 __attribute__((ext_vector_type(4)));

__device__ __forceinline__ uint32_t rotl32(uint32_t v, uint32_t r) {
  return (v << r) | (v >> (32u - r));
}

__device__ __forceinline__ void threefry2x32(uint32_t k0, uint32_t k1,
                                             uint32_t& x0, uint32_t& x1) {
  uint32_t k2 = k0 ^ k1 ^ 0x1BD11BDAu;
  x0 += k0; x1 += k1;
#define TF_R(r) { x0 += x1; x1 = rotl32(x1, r); x1 ^= x0; }
  TF_R(13u) TF_R(15u) TF_R(26u) TF_R(6u)
  x0 += k1; x1 += k2 + 1u;
  TF_R(17u) TF_R(29u) TF_R(16u) TF_R(24u)
  x0 += k2; x1 += k0 + 2u;
  TF_R(13u) TF_R(15u) TF_R(26u) TF_R(6u)
  x0 += k0; x1 += k1 + 3u;
  TF_R(17u) TF_R(29u) TF_R(16u) TF_R(24u)
  x0 += k1; x1 += k2 + 4u;
  TF_R(13u) TF_R(15u) TF_R(26u) TF_R(6u)
  x0 += k2; x1 += k0 + 5u;
#undef TF_R
}

__device__ __forceinline__ double fold_pool_w(const float* W, int base, int pos) {
  int iy = pos / 6, ix = pos % 6;
  double w = 0.0;
  for (int dy = 0; dy < 2; ++dy) {
    int ky = iy - dy; if (ky < 0 || ky > 4) continue;
    for (int dx = 0; dx < 2; ++dx) {
      int kx = ix - dx; if (kx < 0 || kx > 4) continue;
      w += (double)W[base + ky * 5 + kx];
    }
  }
  return w;
}

__device__ __forceinline__ uint16_t f2bf(float x) {  // RNE bf16
  uint32_t u = __float_as_uint(x);
  uint32_t r = (u + 0x7fffu + ((u >> 16) & 1u)) >> 16;
  return (uint16_t)r;
}

// --- prep_all: W1R, W2R, WB1, WB2, cnt zero (blocks < 654), eps (>= 654) --
// W1R [og4][pos36][c3][oj8]; W2R [og4][c32][pos36][oj16]
// WB1 [hl2][ks4][nt2][lane64][j8]; WB2 [hl2][pos36][nt4][lane64][j8]
__global__ __launch_bounds__(256) void prep_all(const float* __restrict__ W_in,
                                                const float* __restrict__ W_h1,
                                                double* __restrict__ W1R,
                                                double* __restrict__ W2R,
                                                uint16_t* __restrict__ WB1,
                                                uint16_t* __restrict__ WB2,
                                                float* __restrict__ EPS,
                                                uint32_t* __restrict__ cnt) {
  if (blockIdx.x < 654) {
    int e = blockIdx.x * 256 + threadIdx.x;
    if (e < 3456) {
      int oj = e & 7, c = (e >> 3) % 3, pos = ((e >> 3) / 3) % 36, og = (e >> 3) / 108;
      int oc = og * 8 + oj;
      W1R[e] = fold_pool_w(W_in, (oc * 3 + c) * 25, pos);
    } else if (e < 77184) {
      int e2 = e - 3456;
      int oj = e2 & 15, pos = (e2 >> 4) % 36, c = ((e2 >> 4) / 36) % 32, og = e2 / 18432;
      int oc = og * 16 + oj;
      W2R[e2] = fold_pool_w(W_h1, (oc * 32 + c) * 25, pos);
    } else if (e < 93568) {
      int e3 = e - 77184;
      int j = e3 & 7, lane = (e3 >> 3) & 63, nt = (e3 >> 9) & 1, ks = (e3 >> 10) & 3, hl = e3 >> 12;
      int k = ks * 32 + (lane >> 4) * 8 + j;
      int oc = nt * 16 + (lane & 15);
      uint16_t val = 0;
      if (k < 108) {
        int c = k / 36, pos = k % 36;
        double w = fold_pool_w(W_in, (oc * 3 + c) * 25, pos);
        uint16_t hi = f2bf((float)w);
        if (hl == 0) val = hi;
        else {
          float hif = __uint_as_float(((uint32_t)hi) << 16);
          val = f2bf((float)(w - (double)hif));
        }
      }
      WB1[e3] = val;
    } else if (e < 167296) {
      int e4 = e - 93568;
      int j = e4 & 7, lane = (e4 >> 3) & 63, nt = (e4 >> 9) & 3, pos = e4 >> 11;
      int oc = nt * 16 + (lane & 15);
      int c  = (lane >> 4) * 8 + j;
      double w = fold_pool_w(W_h1, (oc * 32 + c) * 25, pos);
      uint16_t hi = f2bf((float)w);
      float hif = __uint_as_float(((uint32_t)hi) << 16);
      uint16_t lo = f2bf((float)(w - (double)hif));
      WB2[e4] = hi;
      WB2[73728 + e4] = lo;
    } else if (e < 167298) {
      cnt[e - 167296] = 0;
    }
  } else {
    // eps: wave per oc' (0..95), direct fold from raw weights
    int wid = threadIdx.x >> 6, lane = threadIdx.x & 63;
    int o = (blockIdx.x - 654) * 4 + wid;  // 0..95
    const double u24 = 5.9604644775390625e-08;
    double s = 0.0;
    if (o < 32) {
      for (int t = lane; t < 108; t += 64) {
        int pos = t / 3, c = t % 3;
        s += fabs(fold_pool_w(W_in, (o * 3 + c) * 25, pos));
      }
    } else {
      int oc = o - 32;
      for (int t = lane; t < 1152; t += 64) {
        int c = t / 36, pos = t % 36;
        s += fabs(fold_pool_w(W_h1, (oc * 32 + c) * 25, pos));
      }
    }
    #pragma unroll
    for (int off = 32; off > 0; off >>= 1) s += __shfl_xor(s, off);
    if (lane == 0)
      EPS[o] = (o < 32) ? (float)(s * (108.0 * u24 * 6.0) * 0.25)
                        : (float)(s * (1152.0 * u24 * 6.0) * 0.25);
  }
}

// --- spike gen via ballot: rowm[tb][c][32 rows] u32 -----------------------
__global__ __launch_bounds__(256) void gen_spikes(const float* __restrict__ x,
                                                  uint32_t* __restrict__ rowm) {
  int id = blockIdx.x * 4 + (threadIdx.x >> 6);
  int lane = threadIdx.x & 63;
  int rp = id & 15, c = (id >> 4) % 3, tb = id / 48;
  int pix = rp * 64 + lane;
  int b = tb & 63;
  uint32_t i = (uint32_t)((tb * 3 + c) * 1024 + pix);
  uint32_t x0 = 0u, x1 = i;
  threefry2x32(0u, 1u, x0, x1);
  uint32_t bits = x0 ^ x1;
  float u = __uint_as_float((bits >> 9) | 0x3f800000u) - 1.0f;
  float xv = x[(b * 3 + c) * 1024 + pix];
  unsigned long long mask = __ballot(u < 2.0f * xv);
  if (lane == 0) ((unsigned long long*)rowm)[id] = mask;
}

// --- conv1 via MFMA: in-kernel window build + in-epilogue flag append -----
__global__ __launch_bounds__(256) void conv1_mfma(const uint32_t* __restrict__ rowm,
                                                  const uint16_t* __restrict__ WB1,
                                                  const float* __restrict__ EPS,
                                                  uint32_t* __restrict__ A1w,
                                                  uint32_t* __restrict__ B1w,
                                                  uint32_t* __restrict__ cnt,
                                                  uint32_t* __restrict__ list1) {
  __shared__ uint32_t sR[4][96];
  const int tid = threadIdx.x;
  const int wid = tid >> 6, lane = tid & 63;
  const int tb = blockIdx.x * 4 + wid;
  const int q = lane >> 4, ln = lane & 15;

  for (int i = lane; i < 96; i += 64) sR[wid][i] = rowm[tb * 96 + i];

  const float eps0 = EPS[ln];
  const float eps1 = EPS[16 + ln];

  bf16x8 bf[2][4][2];
  #pragma unroll
  for (int hl = 0; hl < 2; ++hl)
    #pragma unroll
    for (int ks = 0; ks < 4; ++ks)
      #pragma unroll
      for (int nt = 0; nt < 2; ++nt)
        bf[hl][ks][nt] =
            *(const bf16x8*)(WB1 + ((((hl * 4 + ks) * 2 + nt) * 64 + lane) * 8));

  const int wl = lane;
  const int qq = wl >> 2, rr = wl & 3;

  for (int mt = 0; mt < 13; ++mt) {
    int p = mt * 16 + ln;
    int pc = p < 196 ? p : 195;
    int oh = pc / 14, ow = pc % 14;
    // build 108-bit window (k = c*36+pos) from row masks (same as win_prep)
    uint64_t seg0 = 0, seg1 = 0, seg2 = 0;
    #pragma unroll
    for (int iy = 0; iy < 6; ++iy) {
      seg0 |= (uint64_t)((sR[wid][0 * 32 + 2 * oh + iy] >> (2 * ow)) & 0x3fu) << (6 * iy);
      seg1 |= (uint64_t)((sR[wid][1 * 32 + 2 * oh + iy] >> (2 * ow)) & 0x3fu) << (6 * iy);
      seg2 |= (uint64_t)((sR[wid][2 * 32 + 2 * oh + iy] >> (2 * ow)) & 0x3fu) << (6 * iy);
    }
    uint64_t lo = seg0 | (seg1 << 36);
    uint64_t hi = (seg1 >> 28) | (seg2 << 8);
    uint32_t wz[4] = {(uint32_t)lo, (uint32_t)(lo >> 32),
                      (uint32_t)hi, (uint32_t)(hi >> 32)};

    f32x4 acc0 = (f32x4)(0.0f), acc1 = (f32x4)(0.0f);
    #pragma unroll
    for (int ks = 0; ks < 4; ++ks) {
      uint32_t byte = (wz[ks] >> (q * 8)) & 0xffu;
      union { uint32_t u[4]; bf16x8 v; } a;
      #pragma unroll
      for (int i = 0; i < 4; ++i)
        a.u[i] = (((byte >> (2 * i)) & 1u) ? 0x3F80u : 0u) |
                 (((byte >> (2 * i + 1)) & 1u) ? 0x3F800000u : 0u);
      acc0 = __builtin_amdgcn_mfma_f32_16x16x32_bf16(a.v, bf[0][ks][0], acc0, 0, 0, 0);
      acc0 = __builtin_amdgcn_mfma_f32_16x16x32_bf16(a.v, bf[1][ks][0], acc0, 0, 0, 0);
      acc1 = __builtin_amdgcn_mfma_f32_16x16x32_bf16(a.v, bf[0][ks][1], acc1, 0, 0, 0);
      acc1 = __builtin_amdgcn_mfma_f32_16x16x32_bf16(a.v, bf[1][ks][1], acc1, 0, 0, 0);
    }

    unsigned long long bA0[4], bA1[4], bB0[4], bB1[4], bF0[4], bF1[4];
    #pragma unroll
    for (int r = 0; r < 4; ++r) {
      float c0 = acc0[r] * 0.25f;
      float c1 = acc1[r] * 0.25f;
      bA0[r] = __ballot(c0 > 1.0f);
      bB0[r] = __ballot(c0 > 2.0f);
      bF0[r] = __ballot(fabsf(c0 - 1.0f) <= eps0 || fabsf(c0 - 2.0f) <= eps0);
      bA1[r] = __ballot(c1 > 1.0f);
      bB1[r] = __ballot(c1 > 2.0f);
      bF1[r] = __ballot(fabsf(c1 - 1.0f) <= eps1 || fabsf(c1 - 2.0f) <= eps1);
    }

    int pw = mt * 16 + wl;
    if (wl < 16 && pw < 196) {
#define SEL(B) (rr == 0 ? B[0] : rr == 1 ? B[1] : rr == 2 ? B[2] : B[3])
      uint32_t wA = (uint32_t)((SEL(bA0) >> (qq * 16)) & 0xffffull) |
                    ((uint32_t)((SEL(bA1) >> (qq * 16)) & 0xffffull) << 16);
      uint32_t wB = (uint32_t)((SEL(bB0) >> (qq * 16)) & 0xffffull) |
                    ((uint32_t)((SEL(bB1) >> (qq * 16)) & 0xffffull) << 16);
      uint32_t wF = (uint32_t)((SEL(bF0) >> (qq * 16)) & 0xffffull) |
                    ((uint32_t)((SEL(bF1) >> (qq * 16)) & 0xffffull) << 16);
#undef SEL
      uint32_t idx = (uint32_t)(tb * 196 + pw);
      A1w[idx] = wA;
      B1w[idx] = wB;
      if (wF) {  // rare: append flagged bits to worklist
        uint32_t n = (uint32_t)__popc(wF);
        uint32_t slot = atomicAdd(&cnt[0], n);
        uint32_t base = idx * 32u;
        while (wF) {
          int bit = __ffs(wF) - 1; wF &= wF - 1;
          if (slot < CAPF1) list1[slot] = base + (uint32_t)bit;
          ++slot;
        }
      }
    }
  }
}

// --- fix1b: dense worklist, exact f64, single-bit atomic patch ------------
__global__ __launch_bounds__(64) void fix1b(const uint32_t* __restrict__ cnt,
                                            const uint32_t* __restrict__ list,
                                            const uint32_t* __restrict__ rowm,
                                            const double* __restrict__ W1R,
                                            uint32_t* __restrict__ A1w,
                                            uint32_t* __restrict__ B1w) {
  uint32_t total = cnt[0]; if (total > CAPF1) total = CAPF1;
  for (uint32_t i = blockIdx.x * 64 + threadIdx.x; i < total; i += gridDim.x * 64) {
    uint32_t e = list[i];
    uint32_t x = e >> 5;
    int oc = (int)(e & 31u);
    int tb = (int)(x / 196), p = (int)(x % 196);
    int oh = p / 14, ow = p % 14;
    int og = oc >> 3, oj = oc & 7;
    const uint32_t* R = rowm + (size_t)tb * 96;
    double acc = 0.0;
    for (int iy = 0; iy < 6; ++iy)
      for (int ix = 0; ix < 6; ++ix)
        for (int c = 0; c < 3; ++c) {
          double bd = (double)((R[c * 32 + 2 * oh + iy] >> (2 * ow + ix)) & 1u);
          acc = fma(bd, W1R[og * 864 + (iy * 6 + ix) * 24 + c * 8 + oj], acc);
        }
    float cur = (float)(acc * 0.25);
    uint32_t m = 1u << oc;
    if (cur > 1.0f) atomicOr(&A1w[x], m); else atomicAnd(&A1w[x], ~m);
    if (cur > 2.0f) atomicOr(&B1w[x], m); else atomicAnd(&B1w[x], ~m);
  }
}

// --- LIF1 scan (unchanged) -------------------------------------------------
__global__ __launch_bounds__(64) void scan1(const uint32_t* __restrict__ A1w,
                                            const uint32_t* __restrict__ B1w,
                                            uint32_t* __restrict__ mask1) {
  int chain = blockIdx.x * 64 + threadIdx.x;
  if (chain >= NB * 196) return;
  int b = chain / 196, p = chain % 196;
  const size_t stride = (size_t)NB * 196;
  size_t base = (size_t)b * 196 + p;
  uint32_t prev = 0;
  #pragma unroll
  for (int seg = 0; seg < 4; ++seg) {
    uint32_t Abuf[25], Bbuf[25];
    size_t sb = base + (size_t)(seg * 25) * stride;
    #pragma unroll
    for (int i = 0; i < 25; ++i) {
      Abuf[i] = A1w[sb + i * stride];
      Bbuf[i] = B1w[sb + i * stride];
    }
    #pragma unroll
    for (int i = 0; i < 25; ++i) {
      uint32_t s = (Abuf[i] & ~prev) | (Bbuf[i] & prev);
      mask1[sb + i * stride] = s;
      prev = s;
    }
  }
}

// --- conv2 via MFMA: 2 tb per wave, ballot epilogue + flag append ---------
#define CONV2_EPILOG(ACC, TBV)                                                \
  {                                                                           \
    const int w = lane;                                                       \
    const int pw = w >> 1, hfw = w & 1;                                       \
    _Pragma("unroll")                                                         \
    for (int mt2 = 0; mt2 < 2; ++mt2) {                                       \
      const int pt = pw - mt2 * 16;                                           \
      const bool wvalid = (w < 50) && (pt >= 0) && (pt < 16) && (pw < 25);    \
      const int qw = (pt & 15) >> 2, rw = pt & 3;                             \
      uint32_t wA = 0, wB = 0, wF = 0;                                        \
      _Pragma("unroll")                                                       \
      for (int nt = 0; nt < 4; ++nt) {                                        \
        unsigned long long bA[4], bB[4], bF[4];                               \
        _Pragma("unroll")                                                     \
        for (int reg = 0; reg < 4; ++reg) {                                   \
          float c = ACC[mt2 * 4 + nt][reg] * 0.25f;                           \
          float e = epsv[nt];                                                 \
          bA[reg] = __ballot(c > 1.0f);                                       \
          bB[reg] = __ballot(c > 2.0f);                                       \
          bF[reg] = __ballot(fabsf(c - 1.0f) <= e || fabsf(c - 2.0f) <= e);   \
        }                                                                     \
        if (wvalid && (nt >> 1) == hfw) {                                     \
          const int sh = (nt & 1) * 16;                                       \
          unsigned long long sA = rw == 0 ? bA[0] : rw == 1 ? bA[1] : rw == 2 ? bA[2] : bA[3]; \
          unsigned long long sB = rw == 0 ? bB[0] : rw == 1 ? bB[1] : rw == 2 ? bB[2] : bB[3]; \
          unsigned long long sF = rw == 0 ? bF[0] : rw == 1 ? bF[1] : rw == 2 ? bF[2] : bF[3]; \
          wA |= (uint32_t)((sA >> (qw * 16)) & 0xffffull) << sh;              \
          wB |= (uint32_t)((sB >> (qw * 16)) & 0xffffull) << sh;              \
          wF |= (uint32_t)((sF >> (qw * 16)) & 0xffffull) << sh;              \
        }                                                                     \
      }                                                                       \
      if (wvalid) {                                                           \
        uint32_t idx = (uint32_t)((TBV) * 25 + pw) * 2 + hfw;                 \
        A2w[idx] = wA;                                                        \
        B2w[idx] = wB;                                                        \
        if (wF) {                                                             \
          uint32_t n = (uint32_t)__popc(wF);                                  \
          uint32_t slot = atomicAdd(&cnt[1], n);                              \
          uint32_t base2 = idx * 32u;                                         \
          while (wF) {                                                        \
            int bit = __ffs(wF) - 1; wF &= wF - 1;                            \
            if (slot < CAPF2) list2[slot] = base2 + (uint32_t)bit;            \
            ++slot;                                                           \
          }                                                                   \
        }                                                                     \
      }                                                                       \
    }                                                                         \
  }

__global__ __launch_bounds__(256, 3) void conv2_mfma(const uint32_t* __restrict__ mask1,
                                                     const uint16_t* __restrict__ WB,
                                                     const float* __restrict__ EPS,
                                                     uint32_t* __restrict__ A2w,
                                                     uint32_t* __restrict__ B2w,
                                                     uint32_t* __restrict__ cnt,
                                                     uint32_t* __restrict__ list2) {
  __shared__ uint32_t sM[8 * 196];
  const int tid = threadIdx.x;
  const int wid = tid >> 6, lane = tid & 63;
  const int tb0 = blockIdx.x * 8 + wid * 2;   // wave owns tb0, tb0+1

  // wave-local staging (contiguous two tiles); no cross-wave sharing
  for (int i = lane; i < 392; i += 64)
    sM[wid * 392 + i] = mask1[(size_t)tb0 * 196 + i];

  const int q  = lane >> 4;
  const int ln = lane & 15;
  float epsv[4];
  #pragma unroll
  for (int nt = 0; nt < 4; ++nt) epsv[nt] = EPS[32 + nt * 16 + ln];

  const int p0 = ln;
  const int p1 = 16 + ln;
  const bool v1 = (p1 < 25);
  const int oh0 = p0 / 5, ow0 = p0 % 5;
  const int p1c = v1 ? p1 : 0;
  const int oh1 = p1c / 5, ow1 = p1c % 5;

  f32x4 accA[8], accB[8];
  #pragma unroll
  for (int i = 0; i < 8; ++i) { accA[i] = (f32x4)(0.0f); accB[i] = (f32x4)(0.0f); }

  const uint32_t* sW0 = &sM[wid * 392];
  const uint32_t* sW1 = sW0 + 196;

  for (int iy = 0; iy < 6; ++iy) {
    #pragma unroll
    for (int ix = 0; ix < 6; ++ix) {
      const int pos = iy * 6 + ix;
      const int o0 = (2 * oh0 + iy) * 14 + 2 * ow0 + ix;
      const int o1 = (2 * oh1 + iy) * 14 + 2 * ow1 + ix;
      uint32_t w00 = sW0[o0];
      uint32_t w01 = v1 ? sW0[o1] : 0u;
      uint32_t w10 = sW1[o0];
      uint32_t w11 = v1 ? sW1[o1] : 0u;
      uint32_t b00 = (w00 >> (q * 8)) & 0xffu;
      uint32_t b01 = (w01 >> (q * 8)) & 0xffu;
      uint32_t b10 = (w10 >> (q * 8)) & 0xffu;
      uint32_t b11 = (w11 >> (q * 8)) & 0xffu;
      union { uint32_t u[4]; bf16x8 v; } a00, a01, a10, a11;
      #pragma unroll
      for (int i = 0; i < 4; ++i) {
        a00.u[i] = (((b00 >> (2 * i)) & 1u) ? 0x3F80u : 0u) |
                   (((b00 >> (2 * i + 1)) & 1u) ? 0x3F800000u : 0u);
        a01.u[i] = (((b01 >> (2 * i)) & 1u) ? 0x3F80u : 0u) |
                   (((b01 >> (2 * i + 1)) & 1u) ? 0x3F800000u : 0u);
        a10.u[i] = (((b10 >> (2 * i)) & 1u) ? 0x3F80u : 0u) |
                   (((b10 >> (2 * i + 1)) & 1u) ? 0x3F800000u : 0u);
        a11.u[i] = (((b11 >> (2 * i)) & 1u) ? 0x3F80u : 0u) |
                   (((b11 >> (2 * i + 1)) & 1u) ? 0x3F800000u : 0u);
      }
      const uint16_t* bhi_base = WB + (size_t)pos * 2048 + lane * 8;
      const uint16_t* blo_base = bhi_base + 73728;
      #pragma unroll
      for (int nt = 0; nt < 4; ++nt) {
        bf16x8 bhi = *(const bf16x8*)(bhi_base + nt * 512);
        bf16x8 blo = *(const bf16x8*)(blo_base + nt * 512);
        accA[nt] = __builtin_amdgcn_mfma_f32_16x16x32_bf16(a00.v, bhi, accA[nt], 0, 0, 0);
        accA[nt] = __builtin_amdgcn_mfma_f32_16x16x32_bf16(a00.v, blo, accA[nt], 0, 0, 0);
        accA[4 + nt] = __builtin_amdgcn_mfma_f32_16x16x32_bf16(a01.v, bhi, accA[4 + nt], 0, 0, 0);
        accA[4 + nt] = __builtin_amdgcn_mfma_f32_16x16x32_bf16(a01.v, blo, accA[4 + nt], 0, 0, 0);
        accB[nt] = __builtin_amdgcn_mfma_f32_16x16x32_bf16(a10.v, bhi, accB[nt], 0, 0, 0);
        accB[nt] = __builtin_amdgcn_mfma_f32_16x16x32_bf16(a10.v, blo, accB[nt], 0, 0, 0);
        accB[4 + nt] = __builtin_amdgcn_mfma_f32_16x16x32_bf16(a11.v, bhi, accB[4 + nt], 0, 0, 0);
        accB[4 + nt] = __builtin_amdgcn_mfma_f32_16x16x32_bf16(a11.v, blo, accB[4 + nt], 0, 0, 0);
      }
    }
  }

  CONV2_EPILOG(accA, tb0)
  CONV2_EPILOG(accB, (tb0 + 1))
}

// --- fix2b: dense worklist, exact f64, single-bit atomic patch ------------
__global__ __launch_bounds__(64) void fix2b(const uint32_t* __restrict__ cnt,
                                            const uint32_t* __restrict__ list,
                                            const uint32_t* __restrict__ mask1,
                                            const double* __restrict__ W2R,
                                            uint32_t* __restrict__ A2w,
                                            uint32_t* __restrict__ B2w) {
  uint32_t total = cnt[1]; if (total > CAPF2) total = CAPF2;
  for (uint32_t i = blockIdx.x * 64 + threadIdx.x; i < total; i += gridDim.x * 64) {
    uint32_t e = list[i];
    uint32_t wi = e >> 5;
    int bit = (int)(e & 31u);
    uint32_t x = wi >> 1;
    int oc = (int)((wi & 1u) * 32u) + bit;
    int tb = (int)(x / 25), p = (int)(x % 25);
    int oh = p / 5, ow = p % 5;
    int og = oc >> 4, oj = oc & 15;
    const uint32_t* M = mask1 + (size_t)tb * 196;
    double acc = 0.0;
    for (int c = 0; c < 32; ++c)
      for (int iy = 0; iy < 6; ++iy)
        for (int ix = 0; ix < 6; ++ix) {
          uint32_t mm = M[(2 * oh + iy) * 14 + 2 * ow + ix];
          double bd = (double)((mm >> c) & 1u);
          acc = fma(bd, W2R[og * 18432 + c * 576 + (iy * 6 + ix) * 16 + oj], acc);
        }
    float cur = (float)(acc * 0.25);
    uint32_t m = 1u << bit;
    if (cur > 1.0f) atomicOr(&A2w[wi], m); else atomicAnd(&A2w[wi], ~m);
    if (cur > 2.0f) atomicOr(&B2w[wi], m); else atomicAnd(&B2w[wi], ~m);
  }
}

// --- LIF2 scan (unchanged) -------------------------------------------------
__global__ __launch_bounds__(64) void scan2(const uint64_t* __restrict__ A2q,
                                            const uint64_t* __restrict__ B2q,
                                            uint64_t* __restrict__ mask2) {
  int chain = blockIdx.x * 64 + threadIdx.x;
  if (chain >= NB * 25) return;
  int b = chain / 25, p = chain % 25;
  const size_t stride = (size_t)NB * 25;
  size_t base = (size_t)b * 25 + p;
  uint64_t prev = 0;
  #pragma unroll
  for (int seg = 0; seg < 4; ++seg) {
    uint64_t Abuf[25], Bbuf[25];
    size_t sb = base + (size_t)(seg * 25) * stride;
    #pragma unroll
    for (int i = 0; i < 25; ++i) {
      Abuf[i] = A2q[sb + i * stride];
      Bbuf[i] = B2q[sb + i * stride];
    }
    #pragma unroll
    for (int i = 0; i < 25; ++i) {
      uint64_t s = (Abuf[i] & ~prev) | (Bbuf[i] & prev);
      mask2[sb + i * stride] = s;
      prev = s;
    }
  }
}

// --- FC (unchanged) --------------------------------------------------------
__global__ __launch_bounds__(256) void fc_kernel(const uint64_t* __restrict__ mask2,
                                                 const float* __restrict__ W2,
                                                 float* __restrict__ cur3) {
  int gid = blockIdx.x * 256 + threadIdx.x;
  if (gid >= NSTEPS * NB * 80) return;
  int tb = gid / 80, r = gid % 80;
  int o = r >> 3, s = r & 7;
  const uint64_t* m = mask2 + (size_t)tb * 25;
  const float* w = W2 + o * 1600 + s * 200;

  uint64_t mw[25];
  #pragma unroll
  for (int p = 0; p < 25; ++p) mw[p] = m[p];

  const int oc0 = s * 8;
  double acc0 = 0.0, acc1 = 0.0;
  #pragma unroll
  for (int j = 0; j < 8; ++j) {
    const float* wj = w + j * 25;
    double a = 0.0;
    #pragma unroll
    for (int p = 0; p < 25; ++p) {
      double bd = (double)((mw[p] >> (oc0 + j)) & 1ull);
      a = fma(bd, (double)wj[p], a);
    }
    if (j & 1) acc1 += a; else acc0 += a;
  }
  double acc = acc0 + acc1;
  acc += __shfl_xor(acc, 4);
  acc += __shfl_xor(acc, 2);
  acc += __shfl_xor(acc, 1);
  if (s == 0) cur3[tb * 10 + o] = (float)acc;
}

// --- LIF3 (unchanged) ------------------------------------------------------
__global__ __launch_bounds__(64) void lif3_kernel(const float* __restrict__ cur3,
                                                  float* __restrict__ out) {
  int bo = blockIdx.x * 64 + threadIdx.x;
  if (bo >= NB * 10) return;
  float prev = 0.0f;
  #pragma unroll
  for (int seg = 0; seg < 4; ++seg) {
    float cbuf[25];
    #pragma unroll
    for (int i = 0; i < 25; ++i) cbuf[i] = cur3[(seg * 25 + i) * 640 + bo];
    #pragma unroll
    for (int i = 0; i < 25; ++i) {
      int t = seg * 25 + i;
      float mem = cbuf[i] - prev;
      bool s = mem > 1.0f;
      out[t * 640 + bo] = s ? 1.0f : 0.0f;
      out[NSTEPS * 640 + t * 640 + bo] = mem;
      prev = s ? 1.0f : 0.0f;
    }
  }
}

extern "C" void kernel_launch(void* const* d_in, const int* in_sizes, int n_in,
                              void* d_out, int out_size, void* d_ws, size_t ws_size,
                              hipStream_t stream) {
  const float* x    = (const float*)d_in[0];
  const float* W_in = (const float*)d_in[1];
  const float* W_h1 = (const float*)d_in[2];
  const float* W_h2 = (const float*)d_in[3];
  float* out = (float*)d_out;

  unsigned char* ws = (unsigned char*)d_ws;
  double*   W1R   = (double*)(ws + 0);              //     27,648
  double*   W2R   = (double*)(ws + 27648);          //    589,824
  uint16_t* WB1   = (uint16_t*)(ws + 617472);       //     32,768
  uint16_t* WB2   = (uint16_t*)(ws + 650240);       //    294,912
  float*    EPS   = (float*)(ws + 945152);          //        384
  uint32_t* cnt   = (uint32_t*)(ws + 945536);       //          8 (pad)
  uint32_t* rowm  = (uint32_t*)(ws + 945664);       //  2,457,600
  uint32_t* A1w   = (uint32_t*)(ws + 3403264);      //  5,017,600
  uint32_t* B1w   = (uint32_t*)(ws + 8420864);      //  5,017,600
  uint32_t* mask1 = (uint32_t*)(ws + 13438464);     //  5,017,600
  uint32_t* A2w   = (uint32_t*)(ws + 18456064);     //  1,280,000
  uint32_t* B2w   = (uint32_t*)(ws + 19736064);     //  1,280,000
  uint64_t* mask2 = (uint64_t*)(ws + 21016064);     //  1,280,000
  float*    cur3  = (float*)(ws + 22296064);        //    256,000
  uint32_t* list1 = (uint32_t*)(ws + 22552064);     //  2,097,152
  uint32_t* list2 = (uint32_t*)(ws + 24649216);     //  1,048,576 (end ~25.7 MB)

  prep_all<<<678, 256, 0, stream>>>(W_in, W_h1, W1R, W2R, WB1, WB2, EPS, cnt);
  gen_spikes<<<76800, 256, 0, stream>>>(x, rowm);
  conv1_mfma<<<1600, 256, 0, stream>>>(rowm, WB1, EPS, A1w, B1w, cnt, list1);
  fix1b<<<1024, 64, 0, stream>>>(cnt, list1, rowm, W1R, A1w, B1w);
  scan1<<<(NB * 196 + 63) / 64, 64, 0, stream>>>(A1w, B1w, mask1);
  conv2_mfma<<<800, 256, 0, stream>>>(mask1, WB2, EPS, A2w, B2w, cnt, list2);
  fix2b<<<1024, 64, 0, stream>>>(cnt, list2, mask1, W2R, A2w, B2w);
  scan2<<<(NB * 25 + 63) / 64, 64, 0, stream>>>((const uint64_t*)A2w,
                                                (const uint64_t*)B2w, mask2);
  fc_kernel<<<(NSTEPS * NB * 80 + 255) / 256, 256, 0, stream>>>(mask2, W_h2, cur3);
  lif3_kernel<<<10, 64, 0, stream>>>(cur3, out);
}

// Round 15
// 299.309 us; speedup vs baseline: 1.4491x; 1.1688x over previous
//
#include <hip/hip_runtime.h>
#include <stdint.h>

// ---------------------------------------------------------------------------
// Conv-SNN, 100 steps, B=64, BETA=0.
// Round 15: fixup latency fix + one fewer launch.
//  - fix1c/fix2c: lane-parallel exact f64 recompute (8/16 lanes per flagged
//    item, shfl_xor reduce) — r14's fix2b ran a 1152-step serial chain at
//    0.3% occupancy (67 us); f64 reorder accepted per r9 fc precedent.
//  - prep_gen: prep_all + gen_spikes merged (independent block ranges).
// All other kernels byte-identical to round 14 (absmax 0.0 lineage).
// ---------------------------------------------------------------------------

#define NSTEPS 100
#define NB 64
#define CAPF1 524288u
#define CAPF2 262144u

typedef short bf16x8 __attribute__((ext_vector_type(8)));
typedef float f32x4 __attribute__((ext_vector_type(4)));

__device__ __forceinline__ uint32_t rotl32(uint32_t v, uint32_t r) {
  return (v << r) | (v >> (32u - r));
}

__device__ __forceinline__ void threefry2x32(uint32_t k0, uint32_t k1,
                                             uint32_t& x0, uint32_t& x1) {
  uint32_t k2 = k0 ^ k1 ^ 0x1BD11BDAu;
  x0 += k0; x1 += k1;
#define TF_R(r) { x0 += x1; x1 = rotl32(x1, r); x1 ^= x0; }
  TF_R(13u) TF_R(15u) TF_R(26u) TF_R(6u)
  x0 += k1; x1 += k2 + 1u;
  TF_R(17u) TF_R(29u) TF_R(16u) TF_R(24u)
  x0 += k2; x1 += k0 + 2u;
  TF_R(13u) TF_R(15u) TF_R(26u) TF_R(6u)
  x0 += k0; x1 += k1 + 3u;
  TF_R(17u) TF_R(29u) TF_R(16u) TF_R(24u)
  x0 += k1; x1 += k2 + 4u;
  TF_R(13u) TF_R(15u) TF_R(26u) TF_R(6u)
  x0 += k2; x1 += k0 + 5u;
#undef TF_R
}

__device__ __forceinline__ double fold_pool_w(const float* W, int base, int pos) {
  int iy = pos / 6, ix = pos % 6;
  double w = 0.0;
  for (int dy = 0; dy < 2; ++dy) {
    int ky = iy - dy; if (ky < 0 || ky > 4) continue;
    for (int dx = 0; dx < 2; ++dx) {
      int kx = ix - dx; if (kx < 0 || kx > 4) continue;
      w += (double)W[base + ky * 5 + kx];
    }
  }
  return w;
}

__device__ __forceinline__ uint16_t f2bf(float x) {  // RNE bf16
  uint32_t u = __float_as_uint(x);
  uint32_t r = (u + 0x7fffu + ((u >> 16) & 1u)) >> 16;
  return (uint16_t)r;
}

// --- prep_gen: blocks [0,654) weights, [654,678) eps, [678,...) gen_spikes
__global__ __launch_bounds__(256) void prep_gen(const float* __restrict__ W_in,
                                                const float* __restrict__ W_h1,
                                                const float* __restrict__ x,
                                                double* __restrict__ W1R,
                                                double* __restrict__ W2R,
                                                uint16_t* __restrict__ WB1,
                                                uint16_t* __restrict__ WB2,
                                                float* __restrict__ EPS,
                                                uint32_t* __restrict__ cnt,
                                                uint32_t* __restrict__ rowm) {
  if (blockIdx.x >= 678) {
    // gen_spikes (ballot form)
    int id = (blockIdx.x - 678) * 4 + (threadIdx.x >> 6);
    int lane = threadIdx.x & 63;
    int rp = id & 15, c = (id >> 4) % 3, tb = id / 48;
    int pix = rp * 64 + lane;
    int b = tb & 63;
    uint32_t i = (uint32_t)((tb * 3 + c) * 1024 + pix);
    uint32_t x0 = 0u, x1 = i;
    threefry2x32(0u, 1u, x0, x1);
    uint32_t bits = x0 ^ x1;
    float u = __uint_as_float((bits >> 9) | 0x3f800000u) - 1.0f;
    float xv = x[(b * 3 + c) * 1024 + pix];
    unsigned long long mask = __ballot(u < 2.0f * xv);
    if (lane == 0) ((unsigned long long*)rowm)[id] = mask;
    return;
  }
  if (blockIdx.x < 654) {
    int e = blockIdx.x * 256 + threadIdx.x;
    if (e < 3456) {
      int oj = e & 7, c = (e >> 3) % 3, pos = ((e >> 3) / 3) % 36, og = (e >> 3) / 108;
      int oc = og * 8 + oj;
      W1R[e] = fold_pool_w(W_in, (oc * 3 + c) * 25, pos);
    } else if (e < 77184) {
      int e2 = e - 3456;
      int oj = e2 & 15, pos = (e2 >> 4) % 36, c = ((e2 >> 4) / 36) % 32, og = e2 / 18432;
      int oc = og * 16 + oj;
      W2R[e2] = fold_pool_w(W_h1, (oc * 32 + c) * 25, pos);
    } else if (e < 93568) {
      int e3 = e - 77184;
      int j = e3 & 7, lane = (e3 >> 3) & 63, nt = (e3 >> 9) & 1, ks = (e3 >> 10) & 3, hl = e3 >> 12;
      int k = ks * 32 + (lane >> 4) * 8 + j;
      int oc = nt * 16 + (lane & 15);
      uint16_t val = 0;
      if (k < 108) {
        int c = k / 36, pos = k % 36;
        double w = fold_pool_w(W_in, (oc * 3 + c) * 25, pos);
        uint16_t hi = f2bf((float)w);
        if (hl == 0) val = hi;
        else {
          float hif = __uint_as_float(((uint32_t)hi) << 16);
          val = f2bf((float)(w - (double)hif));
        }
      }
      WB1[e3] = val;
    } else if (e < 167296) {
      int e4 = e - 93568;
      int j = e4 & 7, lane = (e4 >> 3) & 63, nt = (e4 >> 9) & 3, pos = e4 >> 11;
      int oc = nt * 16 + (lane & 15);
      int c  = (lane >> 4) * 8 + j;
      double w = fold_pool_w(W_h1, (oc * 32 + c) * 25, pos);
      uint16_t hi = f2bf((float)w);
      float hif = __uint_as_float(((uint32_t)hi) << 16);
      uint16_t lo = f2bf((float)(w - (double)hif));
      WB2[e4] = hi;
      WB2[73728 + e4] = lo;
    } else if (e < 167298) {
      cnt[e - 167296] = 0;
    }
  } else {
    // eps: wave per oc' (0..95)
    int wid = threadIdx.x >> 6, lane = threadIdx.x & 63;
    int o = (blockIdx.x - 654) * 4 + wid;
    const double u24 = 5.9604644775390625e-08;
    double s = 0.0;
    if (o < 32) {
      for (int t = lane; t < 108; t += 64) {
        int pos = t / 3, c = t % 3;
        s += fabs(fold_pool_w(W_in, (o * 3 + c) * 25, pos));
      }
    } else {
      int oc = o - 32;
      for (int t = lane; t < 1152; t += 64) {
        int c = t / 36, pos = t % 36;
        s += fabs(fold_pool_w(W_h1, (oc * 32 + c) * 25, pos));
      }
    }
    #pragma unroll
    for (int off = 32; off > 0; off >>= 1) s += __shfl_xor(s, off);
    if (lane == 0)
      EPS[o] = (o < 32) ? (float)(s * (108.0 * u24 * 6.0) * 0.25)
                        : (float)(s * (1152.0 * u24 * 6.0) * 0.25);
  }
}

// --- conv1 via MFMA (unchanged from r14) ----------------------------------
__global__ __launch_bounds__(256) void conv1_mfma(const uint32_t* __restrict__ rowm,
                                                  const uint16_t* __restrict__ WB1,
                                                  const float* __restrict__ EPS,
                                                  uint32_t* __restrict__ A1w,
                                                  uint32_t* __restrict__ B1w,
                                                  uint32_t* __restrict__ cnt,
                                                  uint32_t* __restrict__ list1) {
  __shared__ uint32_t sR[4][96];
  const int tid = threadIdx.x;
  const int wid = tid >> 6, lane = tid & 63;
  const int tb = blockIdx.x * 4 + wid;
  const int q = lane >> 4, ln = lane & 15;

  for (int i = lane; i < 96; i += 64) sR[wid][i] = rowm[tb * 96 + i];

  const float eps0 = EPS[ln];
  const float eps1 = EPS[16 + ln];

  bf16x8 bf[2][4][2];
  #pragma unroll
  for (int hl = 0; hl < 2; ++hl)
    #pragma unroll
    for (int ks = 0; ks < 4; ++ks)
      #pragma unroll
      for (int nt = 0; nt < 2; ++nt)
        bf[hl][ks][nt] =
            *(const bf16x8*)(WB1 + ((((hl * 4 + ks) * 2 + nt) * 64 + lane) * 8));

  const int wl = lane;
  const int qq = wl >> 2, rr = wl & 3;

  for (int mt = 0; mt < 13; ++mt) {
    int p = mt * 16 + ln;
    int pc = p < 196 ? p : 195;
    int oh = pc / 14, ow = pc % 14;
    uint64_t seg0 = 0, seg1 = 0, seg2 = 0;
    #pragma unroll
    for (int iy = 0; iy < 6; ++iy) {
      seg0 |= (uint64_t)((sR[wid][0 * 32 + 2 * oh + iy] >> (2 * ow)) & 0x3fu) << (6 * iy);
      seg1 |= (uint64_t)((sR[wid][1 * 32 + 2 * oh + iy] >> (2 * ow)) & 0x3fu) << (6 * iy);
      seg2 |= (uint64_t)((sR[wid][2 * 32 + 2 * oh + iy] >> (2 * ow)) & 0x3fu) << (6 * iy);
    }
    uint64_t lo = seg0 | (seg1 << 36);
    uint64_t hi = (seg1 >> 28) | (seg2 << 8);
    uint32_t wz[4] = {(uint32_t)lo, (uint32_t)(lo >> 32),
                      (uint32_t)hi, (uint32_t)(hi >> 32)};

    f32x4 acc0 = (f32x4)(0.0f), acc1 = (f32x4)(0.0f);
    #pragma unroll
    for (int ks = 0; ks < 4; ++ks) {
      uint32_t byte = (wz[ks] >> (q * 8)) & 0xffu;
      union { uint32_t u[4]; bf16x8 v; } a;
      #pragma unroll
      for (int i = 0; i < 4; ++i)
        a.u[i] = (((byte >> (2 * i)) & 1u) ? 0x3F80u : 0u) |
                 (((byte >> (2 * i + 1)) & 1u) ? 0x3F800000u : 0u);
      acc0 = __builtin_amdgcn_mfma_f32_16x16x32_bf16(a.v, bf[0][ks][0], acc0, 0, 0, 0);
      acc0 = __builtin_amdgcn_mfma_f32_16x16x32_bf16(a.v, bf[1][ks][0], acc0, 0, 0, 0);
      acc1 = __builtin_amdgcn_mfma_f32_16x16x32_bf16(a.v, bf[0][ks][1], acc1, 0, 0, 0);
      acc1 = __builtin_amdgcn_mfma_f32_16x16x32_bf16(a.v, bf[1][ks][1], acc1, 0, 0, 0);
    }

    unsigned long long bA0[4], bA1[4], bB0[4], bB1[4], bF0[4], bF1[4];
    #pragma unroll
    for (int r = 0; r < 4; ++r) {
      float c0 = acc0[r] * 0.25f;
      float c1 = acc1[r] * 0.25f;
      bA0[r] = __ballot(c0 > 1.0f);
      bB0[r] = __ballot(c0 > 2.0f);
      bF0[r] = __ballot(fabsf(c0 - 1.0f) <= eps0 || fabsf(c0 - 2.0f) <= eps0);
      bA1[r] = __ballot(c1 > 1.0f);
      bB1[r] = __ballot(c1 > 2.0f);
      bF1[r] = __ballot(fabsf(c1 - 1.0f) <= eps1 || fabsf(c1 - 2.0f) <= eps1);
    }

    int pw = mt * 16 + wl;
    if (wl < 16 && pw < 196) {
#define SEL(B) (rr == 0 ? B[0] : rr == 1 ? B[1] : rr == 2 ? B[2] : B[3])
      uint32_t wA = (uint32_t)((SEL(bA0) >> (qq * 16)) & 0xffffull) |
                    ((uint32_t)((SEL(bA1) >> (qq * 16)) & 0xffffull) << 16);
      uint32_t wB = (uint32_t)((SEL(bB0) >> (qq * 16)) & 0xffffull) |
                    ((uint32_t)((SEL(bB1) >> (qq * 16)) & 0xffffull) << 16);
      uint32_t wF = (uint32_t)((SEL(bF0) >> (qq * 16)) & 0xffffull) |
                    ((uint32_t)((SEL(bF1) >> (qq * 16)) & 0xffffull) << 16);
#undef SEL
      uint32_t idx = (uint32_t)(tb * 196 + pw);
      A1w[idx] = wA;
      B1w[idx] = wB;
      if (wF) {
        uint32_t n = (uint32_t)__popc(wF);
        uint32_t slot = atomicAdd(&cnt[0], n);
        uint32_t base = idx * 32u;
        while (wF) {
          int bit = __ffs(wF) - 1; wF &= wF - 1;
          if (slot < CAPF1) list1[slot] = base + (uint32_t)bit;
          ++slot;
        }
      }
    }
  }
}

// --- fix1c: 8 lanes per flagged item, shfl reduce, atomic patch -----------
__global__ __launch_bounds__(256) void fix1c(const uint32_t* __restrict__ cnt,
                                             const uint32_t* __restrict__ list,
                                             const uint32_t* __restrict__ rowm,
                                             const double* __restrict__ W1R,
                                             uint32_t* __restrict__ A1w,
                                             uint32_t* __restrict__ B1w) {
  uint32_t total = cnt[0]; if (total > CAPF1) total = CAPF1;
  const uint32_t g = blockIdx.x * 32 + (threadIdx.x >> 3);
  const int l = threadIdx.x & 7;
  const uint32_t gstride = gridDim.x * 32;
  for (uint32_t i = g; i < total; i += gstride) {
    uint32_t e = list[i];
    uint32_t x = e >> 5;
    int oc = (int)(e & 31u);
    int tb = (int)(x / 196), p = (int)(x % 196);
    int oh = p / 14, ow = p % 14;
    int og = oc >> 3, oj = oc & 7;
    const uint32_t* R = rowm + (size_t)tb * 96;
    double acc = 0.0;
    for (int t = l; t < 108; t += 8) {          // t = pos*3 + c
      int pos = t / 3, c = t - pos * 3;
      int iy = pos / 6, ix = pos - iy * 6;
      double bd = (double)((R[c * 32 + 2 * oh + iy] >> (2 * ow + ix)) & 1u);
      acc = fma(bd, W1R[og * 864 + pos * 24 + c * 8 + oj], acc);
    }
    acc += __shfl_xor(acc, 1);
    acc += __shfl_xor(acc, 2);
    acc += __shfl_xor(acc, 4);
    if (l == 0) {
      float cur = (float)(acc * 0.25);
      uint32_t m = 1u << oc;
      if (cur > 1.0f) atomicOr(&A1w[x], m); else atomicAnd(&A1w[x], ~m);
      if (cur > 2.0f) atomicOr(&B1w[x], m); else atomicAnd(&B1w[x], ~m);
    }
  }
}

// --- LIF1 scan (unchanged) -------------------------------------------------
__global__ __launch_bounds__(64) void scan1(const uint32_t* __restrict__ A1w,
                                            const uint32_t* __restrict__ B1w,
                                            uint32_t* __restrict__ mask1) {
  int chain = blockIdx.x * 64 + threadIdx.x;
  if (chain >= NB * 196) return;
  int b = chain / 196, p = chain % 196;
  const size_t stride = (size_t)NB * 196;
  size_t base = (size_t)b * 196 + p;
  uint32_t prev = 0;
  #pragma unroll
  for (int seg = 0; seg < 4; ++seg) {
    uint32_t Abuf[25], Bbuf[25];
    size_t sb = base + (size_t)(seg * 25) * stride;
    #pragma unroll
    for (int i = 0; i < 25; ++i) {
      Abuf[i] = A1w[sb + i * stride];
      Bbuf[i] = B1w[sb + i * stride];
    }
    #pragma unroll
    for (int i = 0; i < 25; ++i) {
      uint32_t s = (Abuf[i] & ~prev) | (Bbuf[i] & prev);
      mask1[sb + i * stride] = s;
      prev = s;
    }
  }
}

// --- conv2 via MFMA: 2 tb per wave (unchanged from r14) -------------------
#define CONV2_EPILOG(ACC, TBV)                                                \
  {                                                                           \
    const int w = lane;                                                       \
    const int pw = w >> 1, hfw = w & 1;                                       \
    _Pragma("unroll")                                                         \
    for (int mt2 = 0; mt2 < 2; ++mt2) {                                       \
      const int pt = pw - mt2 * 16;                                           \
      const bool wvalid = (w < 50) && (pt >= 0) && (pt < 16) && (pw < 25);    \
      const int qw = (pt & 15) >> 2, rw = pt & 3;                             \
      uint32_t wA = 0, wB = 0, wF = 0;                                        \
      _Pragma("unroll")                                                       \
      for (int nt = 0; nt < 4; ++nt) {                                        \
        unsigned long long bA[4], bB[4], bF[4];                               \
        _Pragma("unroll")                                                     \
        for (int reg = 0; reg < 4; ++reg) {                                   \
          float c = ACC[mt2 * 4 + nt][reg] * 0.25f;                           \
          float e = epsv[nt];                                                 \
          bA[reg] = __ballot(c > 1.0f);                                       \
          bB[reg] = __ballot(c > 2.0f);                                       \
          bF[reg] = __ballot(fabsf(c - 1.0f) <= e || fabsf(c - 2.0f) <= e);   \
        }                                                                     \
        if (wvalid && (nt >> 1) == hfw) {                                     \
          const int sh = (nt & 1) * 16;                                       \
          unsigned long long sA = rw == 0 ? bA[0] : rw == 1 ? bA[1] : rw == 2 ? bA[2] : bA[3]; \
          unsigned long long sB = rw == 0 ? bB[0] : rw == 1 ? bB[1] : rw == 2 ? bB[2] : bB[3]; \
          unsigned long long sF = rw == 0 ? bF[0] : rw == 1 ? bF[1] : rw == 2 ? bF[2] : bF[3]; \
          wA |= (uint32_t)((sA >> (qw * 16)) & 0xffffull) << sh;              \
          wB |= (uint32_t)((sB >> (qw * 16)) & 0xffffull) << sh;              \
          wF |= (uint32_t)((sF >> (qw * 16)) & 0xffffull) << sh;              \
        }                                                                     \
      }                                                                       \
      if (wvalid) {                                                           \
        uint32_t idx = (uint32_t)((TBV) * 25 + pw) * 2 + hfw;                 \
        A2w[idx] = wA;                                                        \
        B2w[idx] = wB;                                                        \
        if (wF) {                                                             \
          uint32_t n = (uint32_t)__popc(wF);                                  \
          uint32_t slot = atomicAdd(&cnt[1], n);                              \
          uint32_t base2 = idx * 32u;                                         \
          while (wF) {                                                        \
            int bit = __ffs(wF) - 1; wF &= wF - 1;                            \
            if (slot < CAPF2) list2[slot] = base2 + (uint32_t)bit;            \
            ++slot;                                                           \
          }                                                                   \
        }                                                                     \
      }                                                                       \
    }                                                                         \
  }

__global__ __launch_bounds__(256, 3) void conv2_mfma(const uint32_t* __restrict__ mask1,
                                                     const uint16_t* __restrict__ WB,
                                                     const float* __restrict__ EPS,
                                                     uint32_t* __restrict__ A2w,
                                                     uint32_t* __restrict__ B2w,
                                                     uint32_t* __restrict__ cnt,
                                                     uint32_t* __restrict__ list2) {
  __shared__ uint32_t sM[8 * 196];
  const int tid = threadIdx.x;
  const int wid = tid >> 6, lane = tid & 63;
  const int tb0 = blockIdx.x * 8 + wid * 2;

  for (int i = lane; i < 392; i += 64)
    sM[wid * 392 + i] = mask1[(size_t)tb0 * 196 + i];

  const int q  = lane >> 4;
  const int ln = lane & 15;
  float epsv[4];
  #pragma unroll
  for (int nt = 0; nt < 4; ++nt) epsv[nt] = EPS[32 + nt * 16 + ln];

  const int p0 = ln;
  const int p1 = 16 + ln;
  const bool v1 = (p1 < 25);
  const int oh0 = p0 / 5, ow0 = p0 % 5;
  const int p1c = v1 ? p1 : 0;
  const int oh1 = p1c / 5, ow1 = p1c % 5;

  f32x4 accA[8], accB[8];
  #pragma unroll
  for (int i = 0; i < 8; ++i) { accA[i] = (f32x4)(0.0f); accB[i] = (f32x4)(0.0f); }

  const uint32_t* sW0 = &sM[wid * 392];
  const uint32_t* sW1 = sW0 + 196;

  for (int iy = 0; iy < 6; ++iy) {
    #pragma unroll
    for (int ix = 0; ix < 6; ++ix) {
      const int pos = iy * 6 + ix;
      const int o0 = (2 * oh0 + iy) * 14 + 2 * ow0 + ix;
      const int o1 = (2 * oh1 + iy) * 14 + 2 * ow1 + ix;
      uint32_t w00 = sW0[o0];
      uint32_t w01 = v1 ? sW0[o1] : 0u;
      uint32_t w10 = sW1[o0];
      uint32_t w11 = v1 ? sW1[o1] : 0u;
      uint32_t b00 = (w00 >> (q * 8)) & 0xffu;
      uint32_t b01 = (w01 >> (q * 8)) & 0xffu;
      uint32_t b10 = (w10 >> (q * 8)) & 0xffu;
      uint32_t b11 = (w11 >> (q * 8)) & 0xffu;
      union { uint32_t u[4]; bf16x8 v; } a00, a01, a10, a11;
      #pragma unroll
      for (int i = 0; i < 4; ++i) {
        a00.u[i] = (((b00 >> (2 * i)) & 1u) ? 0x3F80u : 0u) |
                   (((b00 >> (2 * i + 1)) & 1u) ? 0x3F800000u : 0u);
        a01.u[i] = (((b01 >> (2 * i)) & 1u) ? 0x3F80u : 0u) |
                   (((b01 >> (2 * i + 1)) & 1u) ? 0x3F800000u : 0u);
        a10.u[i] = (((b10 >> (2 * i)) & 1u) ? 0x3F80u : 0u) |
                   (((b10 >> (2 * i + 1)) & 1u) ? 0x3F800000u : 0u);
        a11.u[i] = (((b11 >> (2 * i)) & 1u) ? 0x3F80u : 0u) |
                   (((b11 >> (2 * i + 1)) & 1u) ? 0x3F800000u : 0u);
      }
      const uint16_t* bhi_base = WB + (size_t)pos * 2048 + lane * 8;
      const uint16_t* blo_base = bhi_base + 73728;
      #pragma unroll
      for (int nt = 0; nt < 4; ++nt) {
        bf16x8 bhi = *(const bf16x8*)(bhi_base + nt * 512);
        bf16x8 blo = *(const bf16x8*)(blo_base + nt * 512);
        accA[nt] = __builtin_amdgcn_mfma_f32_16x16x32_bf16(a00.v, bhi, accA[nt], 0, 0, 0);
        accA[nt] = __builtin_amdgcn_mfma_f32_16x16x32_bf16(a00.v, blo, accA[nt], 0, 0, 0);
        accA[4 + nt] = __builtin_amdgcn_mfma_f32_16x16x32_bf16(a01.v, bhi, accA[4 + nt], 0, 0, 0);
        accA[4 + nt] = __builtin_amdgcn_mfma_f32_16x16x32_bf16(a01.v, blo, accA[4 + nt], 0, 0, 0);
        accB[nt] = __builtin_amdgcn_mfma_f32_16x16x32_bf16(a10.v, bhi, accB[nt], 0, 0, 0);
        accB[nt] = __builtin_amdgcn_mfma_f32_16x16x32_bf16(a10.v, blo, accB[nt], 0, 0, 0);
        accB[4 + nt] = __builtin_amdgcn_mfma_f32_16x16x32_bf16(a11.v, bhi, accB[4 + nt], 0, 0, 0);
        accB[4 + nt] = __builtin_amdgcn_mfma_f32_16x16x32_bf16(a11.v, blo, accB[4 + nt], 0, 0, 0);
      }
    }
  }

  CONV2_EPILOG(accA, tb0)
  CONV2_EPILOG(accB, (tb0 + 1))
}

// --- fix2c: 16 lanes per flagged item, shfl reduce, atomic patch ----------
__global__ __launch_bounds__(256) void fix2c(const uint32_t* __restrict__ cnt,
                                             const uint32_t* __restrict__ list,
                                             const uint32_t* __restrict__ mask1,
                                             const double* __restrict__ W2R,
                                             uint32_t* __restrict__ A2w,
                                             uint32_t* __restrict__ B2w) {
  uint32_t total = cnt[1]; if (total > CAPF2) total = CAPF2;
  const uint32_t g = blockIdx.x * 16 + (threadIdx.x >> 4);
  const int l = threadIdx.x & 15;
  const uint32_t gstride = gridDim.x * 16;
  for (uint32_t i = g; i < total; i += gstride) {
    uint32_t e = list[i];
    uint32_t wi = e >> 5;
    int bit = (int)(e & 31u);
    uint32_t x = wi >> 1;
    int oc = (int)((wi & 1u) * 32u) + bit;
    int tb = (int)(x / 25), p = (int)(x % 25);
    int oh = p / 5, ow = p % 5;
    int og = oc >> 4, oj = oc & 15;
    const uint32_t* M = mask1 + (size_t)tb * 196;
    double acc = 0.0;
    for (int t = l; t < 1152; t += 16) {        // t = c*36 + pos
      int c = t / 36, pos = t - c * 36;
      int iy = pos / 6, ix = pos - iy * 6;
      uint32_t mm = M[(2 * oh + iy) * 14 + 2 * ow + ix];
      double bd = (double)((mm >> c) & 1u);
      acc = fma(bd, W2R[og * 18432 + c * 576 + pos * 16 + oj], acc);
    }
    acc += __shfl_xor(acc, 1);
    acc += __shfl_xor(acc, 2);
    acc += __shfl_xor(acc, 4);
    acc += __shfl_xor(acc, 8);
    if (l == 0) {
      float cur = (float)(acc * 0.25);
      uint32_t m = 1u << bit;
      if (cur > 1.0f) atomicOr(&A2w[wi], m); else atomicAnd(&A2w[wi], ~m);
      if (cur > 2.0f) atomicOr(&B2w[wi], m); else atomicAnd(&B2w[wi], ~m);
    }
  }
}

// --- LIF2 scan (unchanged) -------------------------------------------------
__global__ __launch_bounds__(64) void scan2(const uint64_t* __restrict__ A2q,
                                            const uint64_t* __restrict__ B2q,
                                            uint64_t* __restrict__ mask2) {
  int chain = blockIdx.x * 64 + threadIdx.x;
  if (chain >= NB * 25) return;
  int b = chain / 25, p = chain % 25;
  const size_t stride = (size_t)NB * 25;
  size_t base = (size_t)b * 25 + p;
  uint64_t prev = 0;
  #pragma unroll
  for (int seg = 0; seg < 4; ++seg) {
    uint64_t Abuf[25], Bbuf[25];
    size_t sb = base + (size_t)(seg * 25) * stride;
    #pragma unroll
    for (int i = 0; i < 25; ++i) {
      Abuf[i] = A2q[sb + i * stride];
      Bbuf[i] = B2q[sb + i * stride];
    }
    #pragma unroll
    for (int i = 0; i < 25; ++i) {
      uint64_t s = (Abuf[i] & ~prev) | (Bbuf[i] & prev);
      mask2[sb + i * stride] = s;
      prev = s;
    }
  }
}

// --- FC (unchanged) --------------------------------------------------------
__global__ __launch_bounds__(256) void fc_kernel(const uint64_t* __restrict__ mask2,
                                                 const float* __restrict__ W2,
                                                 float* __restrict__ cur3) {
  int gid = blockIdx.x * 256 + threadIdx.x;
  if (gid >= NSTEPS * NB * 80) return;
  int tb = gid / 80, r = gid % 80;
  int o = r >> 3, s = r & 7;
  const uint64_t* m = mask2 + (size_t)tb * 25;
  const float* w = W2 + o * 1600 + s * 200;

  uint64_t mw[25];
  #pragma unroll
  for (int p = 0; p < 25; ++p) mw[p] = m[p];

  const int oc0 = s * 8;
  double acc0 = 0.0, acc1 = 0.0;
  #pragma unroll
  for (int j = 0; j < 8; ++j) {
    const float* wj = w + j * 25;
    double a = 0.0;
    #pragma unroll
    for (int p = 0; p < 25; ++p) {
      double bd = (double)((mw[p] >> (oc0 + j)) & 1ull);
      a = fma(bd, (double)wj[p], a);
    }
    if (j & 1) acc1 += a; else acc0 += a;
  }
  double acc = acc0 + acc1;
  acc += __shfl_xor(acc, 4);
  acc += __shfl_xor(acc, 2);
  acc += __shfl_xor(acc, 1);
  if (s == 0) cur3[tb * 10 + o] = (float)acc;
}

// --- LIF3 (unchanged) ------------------------------------------------------
__global__ __launch_bounds__(64) void lif3_kernel(const float* __restrict__ cur3,
                                                  float* __restrict__ out) {
  int bo = blockIdx.x * 64 + threadIdx.x;
  if (bo >= NB * 10) return;
  float prev = 0.0f;
  #pragma unroll
  for (int seg = 0; seg < 4; ++seg) {
    float cbuf[25];
    #pragma unroll
    for (int i = 0; i < 25; ++i) cbuf[i] = cur3[(seg * 25 + i) * 640 + bo];
    #pragma unroll
    for (int i = 0; i < 25; ++i) {
      int t = seg * 25 + i;
      float mem = cbuf[i] - prev;
      bool s = mem > 1.0f;
      out[t * 640 + bo] = s ? 1.0f : 0.0f;
      out[NSTEPS * 640 + t * 640 + bo] = mem;
      prev = s ? 1.0f : 0.0f;
    }
  }
}

extern "C" void kernel_launch(void* const* d_in, const int* in_sizes, int n_in,
                              void* d_out, int out_size, void* d_ws, size_t ws_size,
                              hipStream_t stream) {
  const float* x    = (const float*)d_in[0];
  const float* W_in = (const float*)d_in[1];
  const float* W_h1 = (const float*)d_in[2];
  const float* W_h2 = (const float*)d_in[3];
  float* out = (float*)d_out;

  unsigned char* ws = (unsigned char*)d_ws;
  double*   W1R   = (double*)(ws + 0);              //     27,648
  double*   W2R   = (double*)(ws + 27648);          //    589,824
  uint16_t* WB1   = (uint16_t*)(ws + 617472);       //     32,768
  uint16_t* WB2   = (uint16_t*)(ws + 650240);       //    294,912
  float*    EPS   = (float*)(ws + 945152);          //        384
  uint32_t* cnt   = (uint32_t*)(ws + 945536);       //          8 (pad)
  uint32_t* rowm  = (uint32_t*)(ws + 945664);       //  2,457,600
  uint32_t* A1w   = (uint32_t*)(ws + 3403264);      //  5,017,600
  uint32_t* B1w   = (uint32_t*)(ws + 8420864);      //  5,017,600
  uint32_t* mask1 = (uint32_t*)(ws + 13438464);     //  5,017,600
  uint32_t* A2w   = (uint32_t*)(ws + 18456064);     //  1,280,000
  uint32_t* B2w   = (uint32_t*)(ws + 19736064);     //  1,280,000
  uint64_t* mask2 = (uint64_t*)(ws + 21016064);     //  1,280,000
  float*    cur3  = (float*)(ws + 22296064);        //    256,000
  uint32_t* list1 = (uint32_t*)(ws + 22552064);     //  2,097,152
  uint32_t* list2 = (uint32_t*)(ws + 24649216);     //  1,048,576 (end ~25.7 MB)

  prep_gen<<<678 + 76800, 256, 0, stream>>>(W_in, W_h1, x, W1R, W2R, WB1, WB2,
                                            EPS, cnt, rowm);
  conv1_mfma<<<1600, 256, 0, stream>>>(rowm, WB1, EPS, A1w, B1w, cnt, list1);
  fix1c<<<1024, 256, 0, stream>>>(cnt, list1, rowm, W1R, A1w, B1w);
  scan1<<<(NB * 196 + 63) / 64, 64, 0, stream>>>(A1w, B1w, mask1);
  conv2_mfma<<<800, 256, 0, stream>>>(mask1, WB2, EPS, A2w, B2w, cnt, list2);
  fix2c<<<1024, 256, 0, stream>>>(cnt, list2, mask1, W2R, A2w, B2w);
  scan2<<<(NB * 25 + 63) / 64, 64, 0, stream>>>((const uint64_t*)A2w,
                                                (const uint64_t*)B2w, mask2);
  fc_kernel<<<(NSTEPS * NB * 80 + 255) / 256, 256, 0, stream>>>(mask2, W_h2, cur3);
  lif3_kernel<<<10, 64, 0, stream>>>(cur3, out);
}